// Round 1
// baseline (575.767 us; speedup 1.0000x reference)
//
#include <hip/hip_runtime.h>
#include <hip/hip_bf16.h>
#include <math.h>

// Problem constants
#define B_SZ 64
#define S_SZ 2048
#define A_SZ 128
#define DIN 384
#define NH 64      // LRU state dim H
#define DOUT 64
#define NC 32      // chunks per sequence
#define CL 64      // chunk length (NC*CL == S_SZ)
#define NPROJ 192  // u_re(64) | u_im(64) | d(64)

// ---------------------------------------------------------------------------
// K1: proj[m][n] = obs[m][:] . W[n][:], m = b*S+s, n<64: gamma*B_re, n<128:
// gamma*B_im, n>=128: D.  BM=64, BN=192 (full N -> obs read once), BK=32.
// 256 threads, thread tile 4m x 12n.
// ---------------------------------------------------------------------------
__global__ __launch_bounds__(256) void proj_kernel(
        const float* __restrict__ obs, const float* __restrict__ Bre,
        const float* __restrict__ Bim, const float* __restrict__ Dw,
        const float* __restrict__ gamma_log, float* __restrict__ proj) {
    __shared__ float As[32 * 68];      // [k][m], stride 68 (b128-aligned, low conflict)
    __shared__ float Ws[32 * 192];     // [k][n]
    const int tid = threadIdx.x;
    const int m0 = blockIdx.x * 64;
    const int mt = tid & 15;           // m sub-tile
    const int nt = tid >> 4;           // n sub-tile (0..15)

    float acc[4][12];
#pragma unroll
    for (int i = 0; i < 4; ++i)
#pragma unroll
        for (int j = 0; j < 12; ++j) acc[i][j] = 0.f;

    for (int kt = 0; kt < 12; ++kt) {
        const int k0 = kt * 32;
        // stage A tile: 64 rows x 32 k = 512 float4
#pragma unroll
        for (int rr = 0; rr < 2; ++rr) {
            int q = tid + rr * 256;
            int ml = q >> 3;
            int k4 = (q & 7) * 4;
            float4 v = *(const float4*)(obs + (size_t)(m0 + ml) * DIN + k0 + k4);
            As[(k4 + 0) * 68 + ml] = v.x;
            As[(k4 + 1) * 68 + ml] = v.y;
            As[(k4 + 2) * 68 + ml] = v.z;
            As[(k4 + 3) * 68 + ml] = v.w;
        }
        // stage W tile: 192 rows x 32 k = 1536 float4
#pragma unroll
        for (int rr = 0; rr < 6; ++rr) {
            int q = tid + rr * 256;
            int n = q >> 3;
            int k4 = (q & 7) * 4;
            const float* src;
            if (n < 64) src = Bre + (size_t)n * DIN;
            else if (n < 128) src = Bim + (size_t)(n - 64) * DIN;
            else src = Dw + (size_t)(n - 128) * DIN;
            float4 v = *(const float4*)(src + k0 + k4);
            Ws[(k4 + 0) * 192 + n] = v.x;
            Ws[(k4 + 1) * 192 + n] = v.y;
            Ws[(k4 + 2) * 192 + n] = v.z;
            Ws[(k4 + 3) * 192 + n] = v.w;
        }
        __syncthreads();
#pragma unroll 4
        for (int k = 0; k < 32; ++k) {
            float4 a4 = *(float4*)&As[k * 68 + mt * 4];
            float4 w0 = *(float4*)&Ws[k * 192 + nt * 12];
            float4 w1 = *(float4*)&Ws[k * 192 + nt * 12 + 4];
            float4 w2 = *(float4*)&Ws[k * 192 + nt * 12 + 8];
            float a[4] = {a4.x, a4.y, a4.z, a4.w};
            float w[12] = {w0.x, w0.y, w0.z, w0.w, w1.x, w1.y, w1.z, w1.w,
                           w2.x, w2.y, w2.z, w2.w};
#pragma unroll
            for (int i = 0; i < 4; ++i)
#pragma unroll
                for (int j = 0; j < 12; ++j)
                    acc[i][j] = fmaf(a[i], w[j], acc[i][j]);
        }
        __syncthreads();
    }
    // epilogue: gamma scaling for u columns
    float gsc[12];
#pragma unroll
    for (int j = 0; j < 12; ++j) {
        int n = nt * 12 + j;
        gsc[j] = (n < 128) ? expf(gamma_log[n & 63]) : 1.f;
    }
#pragma unroll
    for (int i = 0; i < 4; ++i) {
        int mg = m0 + mt * 4 + i;
        float* dst = proj + (size_t)mg * NPROJ + nt * 12;
#pragma unroll
        for (int jq = 0; jq < 3; ++jq) {
            float4 v;
            v.x = acc[i][jq * 4 + 0] * gsc[jq * 4 + 0];
            v.y = acc[i][jq * 4 + 1] * gsc[jq * 4 + 1];
            v.z = acc[i][jq * 4 + 2] * gsc[jq * 4 + 2];
            v.w = acc[i][jq * 4 + 3] * gsc[jq * 4 + 3];
            *(float4*)(dst + jq * 4) = v;
        }
    }
}

// ---------------------------------------------------------------------------
// K2: per-(b,chunk) zero-init local scan over CL steps -> carry[b][c][h]
// block = 64 threads (thread h), grid = B*NC
// ---------------------------------------------------------------------------
__global__ __launch_bounds__(64) void carry_kernel(
        const float* __restrict__ proj, const float* __restrict__ nu_log,
        const float* __restrict__ theta_log, float* __restrict__ carr) {
    const int bc = blockIdx.x;
    const int b = bc >> 5;
    const int c = bc & 31;
    const int h = threadIdx.x;
    const float nu = expf(nu_log[h]);
    const float rr = expf(-nu);
    const float th = expf(theta_log[h]);
    const float lre = rr * cosf(th), lim = rr * sinf(th);
    const float* pb = proj + (size_t)(b * S_SZ + c * CL) * NPROJ;
    float hre = 0.f, him = 0.f;
    for (int g = 0; g < CL / 8; ++g) {
        float ur[8], ui[8];
#pragma unroll
        for (int i = 0; i < 8; ++i) {
            ur[i] = pb[(g * 8 + i) * NPROJ + h];
            ui[i] = pb[(g * 8 + i) * NPROJ + 64 + h];
        }
#pragma unroll
        for (int i = 0; i < 8; ++i) {
            float t = fmaf(lre, hre, fmaf(-lim, him, ur[i]));
            him = fmaf(lre, him, fmaf(lim, hre, ui[i]));
            hre = t;
        }
    }
    carr[(size_t)bc * 128 + h] = hre;
    carr[(size_t)bc * 128 + 64 + h] = him;
}

// ---------------------------------------------------------------------------
// K3: per-(b,chunk): combine carries -> H_init, redo scan storing h in LDS,
// then y[s][o] = Re(C h) + d, running max over s -> pmax[b][c][o].
// 256 threads: wave0 scans, waves1/2 stage C^T, then all do 4s x 4o tiles.
// ---------------------------------------------------------------------------
__global__ __launch_bounds__(256) void ymax_kernel(
        const float* __restrict__ proj, const float* __restrict__ carr,
        const float* __restrict__ nu_log, const float* __restrict__ theta_log,
        const float* __restrict__ Cre, const float* __restrict__ Cim,
        float* __restrict__ pmax) {
    __shared__ float hreL[64 * 68];   // [h][s] stride 68
    __shared__ float himL[64 * 68];
    __shared__ float ctre[64 * 68];   // [h][o] stride 68 (transposed C)
    __shared__ float ctim[64 * 68];
    __shared__ float red[16 * 64];
    const int bc = blockIdx.x;
    const int b = bc >> 5;
    const int c = bc & 31;
    const int tid = threadIdx.x;

    if (tid >= 64 && tid < 128) {        // wave1: stage ct_re (overlaps wave0 scan)
        int l = tid - 64;
#pragma unroll 8
        for (int j = 0; j < 64; ++j) ctre[j * 68 + l] = Cre[l * 64 + j];
    } else if (tid >= 128 && tid < 192) { // wave2: stage ct_im
        int l = tid - 128;
#pragma unroll 8
        for (int j = 0; j < 64; ++j) ctim[j * 68 + l] = Cim[l * 64 + j];
    }

    if (tid < 64) {                       // wave0: the scan
        const int h = tid;
        const float nu = expf(nu_log[h]);
        const float rr = expf(-nu);
        const float th = expf(theta_log[h]);
        const float lre = rr * cosf(th), lim = rr * sinf(th);
        // lam^CL
        const float rL = expf(-(float)CL * nu);
        const float aL = (float)CL * th;
        const float Lre = rL * cosf(aL), Lim = rL * sinf(aL);
        // H_init = scan of previous chunks' carries
        float Hre = 0.f, Him = 0.f;
#pragma unroll 8
        for (int cc = 0; cc < c; ++cc) {
            float cr = carr[(size_t)(b * NC + cc) * 128 + h];
            float ci = carr[(size_t)(b * NC + cc) * 128 + 64 + h];
            float t = fmaf(Lre, Hre, fmaf(-Lim, Him, cr));
            Him = fmaf(Lre, Him, fmaf(Lim, Hre, ci));
            Hre = t;
        }
        const float* pb = proj + (size_t)(b * S_SZ + c * CL) * NPROJ;
        float hre = Hre, him = Him;
        for (int g = 0; g < CL / 8; ++g) {
            float ur[8], ui[8];
#pragma unroll
            for (int i = 0; i < 8; ++i) {
                ur[i] = pb[(g * 8 + i) * NPROJ + h];
                ui[i] = pb[(g * 8 + i) * NPROJ + 64 + h];
            }
            float wr[8], wi[8];
#pragma unroll
            for (int i = 0; i < 8; ++i) {
                float t = fmaf(lre, hre, fmaf(-lim, him, ur[i]));
                him = fmaf(lre, him, fmaf(lim, hre, ui[i]));
                hre = t;
                wr[i] = hre; wi[i] = him;
            }
            *(float4*)&hreL[h * 68 + g * 8]     = make_float4(wr[0], wr[1], wr[2], wr[3]);
            *(float4*)&hreL[h * 68 + g * 8 + 4] = make_float4(wr[4], wr[5], wr[6], wr[7]);
            *(float4*)&himL[h * 68 + g * 8]     = make_float4(wi[0], wi[1], wi[2], wi[3]);
            *(float4*)&himL[h * 68 + g * 8 + 4] = make_float4(wi[4], wi[5], wi[6], wi[7]);
        }
    }

    // everyone: issue d-loads early (independent of LDS)
    const int st = tid & 15, ot = tid >> 4;
    const float* db = proj + (size_t)(b * S_SZ + c * CL) * NPROJ;
    float4 dreg[4];
#pragma unroll
    for (int i = 0; i < 4; ++i)
        dreg[i] = *(const float4*)(db + (st * 4 + i) * NPROJ + 128 + ot * 4);

    __syncthreads();

    float acc[4][4];
#pragma unroll
    for (int i = 0; i < 4; ++i) {
        acc[i][0] = dreg[i].x; acc[i][1] = dreg[i].y;
        acc[i][2] = dreg[i].z; acc[i][3] = dreg[i].w;
    }
#pragma unroll 4
    for (int h = 0; h < 64; ++h) {
        float4 hr4 = *(float4*)&hreL[h * 68 + st * 4];
        float4 hi4 = *(float4*)&himL[h * 68 + st * 4];
        float4 cr4 = *(float4*)&ctre[h * 68 + ot * 4];
        float4 ci4 = *(float4*)&ctim[h * 68 + ot * 4];
        float hr[4] = {hr4.x, hr4.y, hr4.z, hr4.w};
        float hi[4] = {hi4.x, hi4.y, hi4.z, hi4.w};
        float cr[4] = {cr4.x, cr4.y, cr4.z, cr4.w};
        float ci[4] = {ci4.x, ci4.y, ci4.z, ci4.w};
#pragma unroll
        for (int i = 0; i < 4; ++i)
#pragma unroll
            for (int j = 0; j < 4; ++j)
                acc[i][j] = fmaf(hr[i], cr[j], fmaf(-hi[i], ci[j], acc[i][j]));
    }
#pragma unroll
    for (int j = 0; j < 4; ++j) {
        float m = fmaxf(fmaxf(acc[0][j], acc[1][j]), fmaxf(acc[2][j], acc[3][j]));
        red[st * 64 + ot * 4 + j] = m;
    }
    __syncthreads();
    if (tid < 64) {
        float mx = red[tid];
#pragma unroll
        for (int q = 1; q < 16; ++q) mx = fmaxf(mx, red[q * 64 + tid]);
        pmax[(size_t)bc * 64 + tid] = mx;
    }
}

// ---------------------------------------------------------------------------
// K4: latent[b][o] = max over chunks of pmax
// ---------------------------------------------------------------------------
__global__ __launch_bounds__(64) void latent_kernel(
        const float* __restrict__ pmax, float* __restrict__ latent) {
    const int b = blockIdx.x;
    const int o = threadIdx.x;
    float mx = -1e30f;
#pragma unroll 8
    for (int c = 0; c < NC; ++c)
        mx = fmaxf(mx, pmax[(size_t)(b * NC + c) * 64 + o]);
    latent[b * 64 + o] = mx;
}

// ---------------------------------------------------------------------------
// K5: fused MLP head. Block = 64 rows (half a batch entry), 256 threads.
// GEMM1 [64m x 448k x 64n] + tanh -> GEMM2 [64k x 32n] + tanh -> dot W3 -> tanh
// ---------------------------------------------------------------------------
__global__ __launch_bounds__(256) void mlp_kernel(
        const float* __restrict__ latent, const float* __restrict__ act,
        const float* __restrict__ W1, const float* __restrict__ b1,
        const float* __restrict__ W2, const float* __restrict__ b2,
        const float* __restrict__ W3, const float* __restrict__ b3,
        float* __restrict__ out) {
    __shared__ float As[64 * 68];      // [k][m]
    __shared__ float Ws[64 * 68];      // [k][n]
    __shared__ float l1L[64 * 65];     // [m][n]
    __shared__ float w2L[64 * 36];     // [k][n2]
    __shared__ float red2[64 * 4];
    const int tid = threadIdx.x;
    const int m0 = blockIdx.x * 64;
    const int b = m0 >> 7;
    const int m = tid & 63;
    const int ng = tid >> 6;           // wave-uniform

    float acc[16];
#pragma unroll
    for (int j = 0; j < 16; ++j) acc[j] = 0.f;

    for (int kt = 0; kt < 7; ++kt) {
        const int k0 = kt * 64;
        // stage X tile: x[m][f] = f<64 ? latent[b][f] : act[b][a(m)][f-64]
#pragma unroll
        for (int rr = 0; rr < 16; ++rr) {
            int e = tid + rr * 256;
            int ml = e >> 6, kk = e & 63;
            int f = k0 + kk;
            float v;
            if (f < 64) {
                v = latent[b * 64 + f];
            } else {
                int a = (m0 + ml) & 127;
                v = act[((size_t)(b * A_SZ + a)) * DIN + (f - 64)];
            }
            As[kk * 68 + ml] = v;
        }
        // stage W1 tile transposed
#pragma unroll
        for (int rr = 0; rr < 16; ++rr) {
            int e = tid + rr * 256;
            int n = e >> 6, kk = e & 63;
            Ws[kk * 68 + n] = W1[n * 448 + k0 + kk];
        }
        __syncthreads();
#pragma unroll 4
        for (int kk = 0; kk < 64; ++kk) {
            float a = As[kk * 68 + m];
#pragma unroll
            for (int jq = 0; jq < 4; ++jq) {
                float4 w = *(float4*)&Ws[kk * 68 + ng * 16 + jq * 4];
                acc[jq * 4 + 0] = fmaf(a, w.x, acc[jq * 4 + 0]);
                acc[jq * 4 + 1] = fmaf(a, w.y, acc[jq * 4 + 1]);
                acc[jq * 4 + 2] = fmaf(a, w.z, acc[jq * 4 + 2]);
                acc[jq * 4 + 3] = fmaf(a, w.w, acc[jq * 4 + 3]);
            }
        }
        __syncthreads();
    }
    // tanh + write l1
#pragma unroll
    for (int j = 0; j < 16; ++j) {
        int n = ng * 16 + j;
        l1L[m * 65 + n] = tanhf(acc[j] + b1[n]);
    }
    // stage W2 transposed
#pragma unroll
    for (int rr = 0; rr < 8; ++rr) {
        int e = tid + rr * 256;
        int n2 = e >> 6, kk = e & 63;
        w2L[kk * 36 + n2] = W2[n2 * 64 + kk];
    }
    __syncthreads();
    float acc2[8];
#pragma unroll
    for (int j = 0; j < 8; ++j) acc2[j] = 0.f;
#pragma unroll 4
    for (int kk = 0; kk < 64; ++kk) {
        float v = l1L[m * 65 + kk];
        float4 wa = *(float4*)&w2L[kk * 36 + ng * 8];
        float4 wb = *(float4*)&w2L[kk * 36 + ng * 8 + 4];
        float w[8] = {wa.x, wa.y, wa.z, wa.w, wb.x, wb.y, wb.z, wb.w};
#pragma unroll
        for (int j = 0; j < 8; ++j) acc2[j] = fmaf(v, w[j], acc2[j]);
    }
    float part = 0.f;
#pragma unroll
    for (int j = 0; j < 8; ++j) {
        int n2 = ng * 8 + j;
        part += tanhf(acc2[j] + b2[n2]) * W3[n2];
    }
    red2[m * 4 + ng] = part;
    __syncthreads();
    if (tid < 64) {
        float s = red2[tid * 4 + 0] + red2[tid * 4 + 1] +
                  red2[tid * 4 + 2] + red2[tid * 4 + 3];
        out[m0 + tid] = tanhf(s + b3[0]);
    }
}

// ---------------------------------------------------------------------------
extern "C" void kernel_launch(void* const* d_in, const int* in_sizes, int n_in,
                              void* d_out, int out_size, void* d_ws, size_t ws_size,
                              hipStream_t stream) {
    (void)in_sizes; (void)n_in; (void)out_size; (void)ws_size;
    const float* obs       = (const float*)d_in[0];
    const float* act       = (const float*)d_in[1];
    const float* nu_log    = (const float*)d_in[2];
    const float* theta_log = (const float*)d_in[3];
    const float* gamma_log = (const float*)d_in[4];
    const float* Bre       = (const float*)d_in[5];
    const float* Bim       = (const float*)d_in[6];
    const float* Cre       = (const float*)d_in[7];
    const float* Cim       = (const float*)d_in[8];
    const float* Dw        = (const float*)d_in[9];
    const float* W1        = (const float*)d_in[10];
    const float* b1        = (const float*)d_in[11];
    const float* W2        = (const float*)d_in[12];
    const float* b2        = (const float*)d_in[13];
    const float* W3        = (const float*)d_in[14];
    const float* b3        = (const float*)d_in[15];
    float* outp = (float*)d_out;

    // workspace layout (floats): proj 25165824 | carr 262144 | pmax 131072 | latent 4096
    // total = 25563136 floats = 102,252,544 bytes
    float* proj   = (float*)d_ws;
    float* carr   = proj + (size_t)25165824;
    float* pmaxb  = carr + 262144;
    float* latent = pmaxb + 131072;

    proj_kernel<<<dim3((B_SZ * S_SZ) / 64), dim3(256), 0, stream>>>(
        obs, Bre, Bim, Dw, gamma_log, proj);
    carry_kernel<<<dim3(B_SZ * NC), dim3(64), 0, stream>>>(
        proj, nu_log, theta_log, carr);
    ymax_kernel<<<dim3(B_SZ * NC), dim3(256), 0, stream>>>(
        proj, carr, nu_log, theta_log, Cre, Cim, pmaxb);
    latent_kernel<<<dim3(B_SZ), dim3(64), 0, stream>>>(pmaxb, latent);
    mlp_kernel<<<dim3((B_SZ * A_SZ) / 64), dim3(256), 0, stream>>>(
        latent, act, W1, b1, W2, b2, W3, b3, outp);
}

// Round 2
// 462.682 us; speedup vs baseline: 1.2444x; 1.2444x over previous
//
#include <hip/hip_runtime.h>
#include <hip/hip_bf16.h>
#include <math.h>

// Problem constants
#define B_SZ 64
#define S_SZ 2048
#define A_SZ 128
#define DIN 384
#define NH 64      // LRU state dim H
#define DOUT 64
#define NC 32      // chunks per sequence
#define CL 64      // chunk length (NC*CL == S_SZ)
#define NPROJ 192  // u_re(64) | u_im(64) | d(64)

typedef __attribute__((ext_vector_type(8))) short s16x8;
typedef __attribute__((ext_vector_type(8))) unsigned short u16x8;
typedef __attribute__((ext_vector_type(4))) float f32x4;

__device__ inline ushort f2bf(float x) {
    __hip_bfloat16 h = __float2bfloat16(x);
    return *reinterpret_cast<ushort*>(&h);
}
__device__ inline float bf2f(ushort u) {
    union { unsigned int i; float f; } c; c.i = ((unsigned int)u) << 16; return c.f;
}

// ---------------------------------------------------------------------------
// K0: pack W = [gamma*B_re ; gamma*B_im ; D] into split-bf16 (hi, lo), layout
// [kt][n][40] (k-tile-major, rows padded to 40, pad = 0). 92160 elems each.
// ---------------------------------------------------------------------------
__global__ __launch_bounds__(256) void pack_w_kernel(
        const float* __restrict__ Bre, const float* __restrict__ Bim,
        const float* __restrict__ Dw, const float* __restrict__ gamma_log,
        ushort* __restrict__ Whi, ushort* __restrict__ Wlo) {
    int idx = blockIdx.x * 256 + threadIdx.x;
    if (idx >= 12 * 192 * 40) return;
    int kk = idx % 40;
    int n  = (idx / 40) % 192;
    int kt = idx / (40 * 192);
    float v = 0.f;
    if (kk < 32) {
        int k = kt * 32 + kk;
        if (n < 64)       v = Bre[n * DIN + k] * expf(gamma_log[n]);
        else if (n < 128) v = Bim[(n - 64) * DIN + k] * expf(gamma_log[n - 64]);
        else              v = Dw[(n - 128) * DIN + k];
    }
    ushort h = f2bf(v);
    ushort l = f2bf(v - bf2f(h));
    Whi[idx] = h;
    Wlo[idx] = l;
}

// ---------------------------------------------------------------------------
// K1: proj[m][n] via split-bf16 MFMA. M=131072, K=384, N=192.
// BM=128, BN=192 (full N), BK=32, 4 waves; wave w owns rows [w*32, w*32+32).
// 3-product hi/lo for fp32-class accuracy. A prefetched global->reg across
// the barrier, W staged from the pre-packed padded layout.
// ---------------------------------------------------------------------------
__global__ __launch_bounds__(256) void proj_mfma_kernel(
        const float* __restrict__ obs, const ushort* __restrict__ Whi,
        const ushort* __restrict__ Wlo, float* __restrict__ proj) {
    __shared__ ushort Ahi[128 * 40];   // [row][40], 10240 B
    __shared__ ushort Alo[128 * 40];
    __shared__ ushort WhiL[192 * 40];  // [n][40], 15360 B
    __shared__ ushort WloL[192 * 40];

    const int tid  = threadIdx.x;
    const int wid  = tid >> 6;
    const int lane = tid & 63;
    const int lrow = lane & 15;
    const int kgrp = lane >> 4;        // 0..3
    const size_t m0 = (size_t)blockIdx.x * 128;

    const int arow  = tid >> 3;        // 0..31 (plus 32*i)
    const int acol4 = (tid & 7) * 4;   // k offset within tile

    f32x4 acc[2][12];
#pragma unroll
    for (int mi = 0; mi < 2; ++mi)
#pragma unroll
        for (int ni = 0; ni < 12; ++ni) acc[mi][ni] = (f32x4){0.f, 0.f, 0.f, 0.f};

#define LOADA(R, KT) do {                                                     \
    const float* base_ = obs + (m0 + arow) * DIN + (KT) * 32 + acol4;         \
    R[0] = *(const float4*)(base_);                                           \
    R[1] = *(const float4*)(base_ + (size_t)32 * DIN);                        \
    R[2] = *(const float4*)(base_ + (size_t)64 * DIN);                        \
    R[3] = *(const float4*)(base_ + (size_t)96 * DIN);                        \
} while (0)

#define WRITEA(R) do {                                                        \
    _Pragma("unroll")                                                         \
    for (int i_ = 0; i_ < 4; ++i_) {                                          \
        int row_ = arow + 32 * i_;                                            \
        ushort4 h_, l_;                                                       \
        h_.x = f2bf(R[i_].x); l_.x = f2bf(R[i_].x - bf2f(h_.x));              \
        h_.y = f2bf(R[i_].y); l_.y = f2bf(R[i_].y - bf2f(h_.y));              \
        h_.z = f2bf(R[i_].z); l_.z = f2bf(R[i_].z - bf2f(h_.z));              \
        h_.w = f2bf(R[i_].w); l_.w = f2bf(R[i_].w - bf2f(h_.w));              \
        *(ushort4*)&Ahi[row_ * 40 + acol4] = h_;                              \
        *(ushort4*)&Alo[row_ * 40 + acol4] = l_;                              \
    }                                                                         \
} while (0)

#define STAGEW(KT) do {                                                       \
    const u16x8* gh_ = (const u16x8*)(Whi + (size_t)(KT) * 7680);             \
    const u16x8* gl_ = (const u16x8*)(Wlo + (size_t)(KT) * 7680);             \
    for (int c_ = tid; c_ < 960; c_ += 256) {                                 \
        *(u16x8*)&WhiL[c_ * 8] = gh_[c_];                                     \
        *(u16x8*)&WloL[c_ * 8] = gl_[c_];                                     \
    }                                                                         \
} while (0)

#define COMPUTE() do {                                                        \
    s16x8 ah0 = *(const s16x8*)&Ahi[(wid * 32 + lrow) * 40 + kgrp * 8];       \
    s16x8 ah1 = *(const s16x8*)&Ahi[(wid * 32 + 16 + lrow) * 40 + kgrp * 8];  \
    s16x8 al0 = *(const s16x8*)&Alo[(wid * 32 + lrow) * 40 + kgrp * 8];       \
    s16x8 al1 = *(const s16x8*)&Alo[(wid * 32 + 16 + lrow) * 40 + kgrp * 8];  \
    _Pragma("unroll")                                                         \
    for (int ni = 0; ni < 12; ++ni) {                                         \
        s16x8 bh = *(const s16x8*)&WhiL[(ni * 16 + lrow) * 40 + kgrp * 8];    \
        s16x8 bl = *(const s16x8*)&WloL[(ni * 16 + lrow) * 40 + kgrp * 8];    \
        acc[0][ni] = __builtin_amdgcn_mfma_f32_16x16x32_bf16(ah0, bh, acc[0][ni], 0, 0, 0); \
        acc[1][ni] = __builtin_amdgcn_mfma_f32_16x16x32_bf16(ah1, bh, acc[1][ni], 0, 0, 0); \
        acc[0][ni] = __builtin_amdgcn_mfma_f32_16x16x32_bf16(al0, bh, acc[0][ni], 0, 0, 0); \
        acc[1][ni] = __builtin_amdgcn_mfma_f32_16x16x32_bf16(al1, bh, acc[1][ni], 0, 0, 0); \
        acc[0][ni] = __builtin_amdgcn_mfma_f32_16x16x32_bf16(ah0, bl, acc[0][ni], 0, 0, 0); \
        acc[1][ni] = __builtin_amdgcn_mfma_f32_16x16x32_bf16(ah1, bl, acc[1][ni], 0, 0, 0); \
    }                                                                         \
} while (0)

    float4 ra[4], rb[4];
    LOADA(ra, 0);
#pragma unroll
    for (int kt2 = 0; kt2 < 6; ++kt2) {
        const int kt = kt2 * 2;
        WRITEA(ra);
        STAGEW(kt);
        LOADA(rb, kt + 1);
        __syncthreads();
        COMPUTE();
        __syncthreads();
        WRITEA(rb);
        STAGEW(kt + 1);
        if (kt + 2 < 12) LOADA(ra, kt + 2);
        __syncthreads();
        COMPUTE();
        __syncthreads();
    }

    // epilogue: D[row=(kgrp*4+reg), col=lrow] per fragment
#pragma unroll
    for (int ni = 0; ni < 12; ++ni) {
        const int col = ni * 16 + lrow;
#pragma unroll
        for (int mi = 0; mi < 2; ++mi) {
            const size_t rbase = m0 + wid * 32 + mi * 16 + kgrp * 4;
            f32x4 a = acc[mi][ni];
#pragma unroll
            for (int r = 0; r < 4; ++r)
                proj[(rbase + r) * NPROJ + col] = a[r];
        }
    }
#undef LOADA
#undef WRITEA
#undef STAGEW
#undef COMPUTE
}

// ---------------------------------------------------------------------------
// K2: per-(b,chunk) zero-init local scan over CL steps -> carry[b][c][h]
// ---------------------------------------------------------------------------
__global__ __launch_bounds__(64) void carry_kernel(
        const float* __restrict__ proj, const float* __restrict__ nu_log,
        const float* __restrict__ theta_log, float* __restrict__ carr) {
    const int bc = blockIdx.x;
    const int b = bc >> 5;
    const int c = bc & 31;
    const int h = threadIdx.x;
    const float nu = expf(nu_log[h]);
    const float rr = expf(-nu);
    const float th = expf(theta_log[h]);
    const float lre = rr * cosf(th), lim = rr * sinf(th);
    const float* pb = proj + (size_t)(b * S_SZ + c * CL) * NPROJ;
    float hre = 0.f, him = 0.f;
    for (int g = 0; g < CL / 8; ++g) {
        float ur[8], ui[8];
#pragma unroll
        for (int i = 0; i < 8; ++i) {
            ur[i] = pb[(g * 8 + i) * NPROJ + h];
            ui[i] = pb[(g * 8 + i) * NPROJ + 64 + h];
        }
#pragma unroll
        for (int i = 0; i < 8; ++i) {
            float t = fmaf(lre, hre, fmaf(-lim, him, ur[i]));
            him = fmaf(lre, him, fmaf(lim, hre, ui[i]));
            hre = t;
        }
    }
    carr[(size_t)bc * 128 + h] = hre;
    carr[(size_t)bc * 128 + 64 + h] = him;
}

// ---------------------------------------------------------------------------
// K3: per-(b,chunk): combine carries -> H_init, redo scan storing h in LDS,
// then y[s][o] = Re(C h) + d, running max over s -> pmax[b][c][o].
// ---------------------------------------------------------------------------
__global__ __launch_bounds__(256) void ymax_kernel(
        const float* __restrict__ proj, const float* __restrict__ carr,
        const float* __restrict__ nu_log, const float* __restrict__ theta_log,
        const float* __restrict__ Cre, const float* __restrict__ Cim,
        float* __restrict__ pmax) {
    __shared__ float hreL[64 * 68];   // [h][s] stride 68
    __shared__ float himL[64 * 68];
    __shared__ float ctre[64 * 68];   // [h][o] stride 68 (transposed C)
    __shared__ float ctim[64 * 68];
    __shared__ float red[16 * 64];
    const int bc = blockIdx.x;
    const int b = bc >> 5;
    const int c = bc & 31;
    const int tid = threadIdx.x;

    if (tid >= 64 && tid < 128) {        // wave1: stage ct_re
        int l = tid - 64;
#pragma unroll 8
        for (int j = 0; j < 64; ++j) ctre[j * 68 + l] = Cre[l * 64 + j];
    } else if (tid >= 128 && tid < 192) { // wave2: stage ct_im
        int l = tid - 128;
#pragma unroll 8
        for (int j = 0; j < 64; ++j) ctim[j * 68 + l] = Cim[l * 64 + j];
    }

    if (tid < 64) {                       // wave0: the scan
        const int h = tid;
        const float nu = expf(nu_log[h]);
        const float rr = expf(-nu);
        const float th = expf(theta_log[h]);
        const float lre = rr * cosf(th), lim = rr * sinf(th);
        const float rL = expf(-(float)CL * nu);
        const float aL = (float)CL * th;
        const float Lre = rL * cosf(aL), Lim = rL * sinf(aL);
        float Hre = 0.f, Him = 0.f;
#pragma unroll 8
        for (int cc = 0; cc < c; ++cc) {
            float cr = carr[(size_t)(b * NC + cc) * 128 + h];
            float ci = carr[(size_t)(b * NC + cc) * 128 + 64 + h];
            float t = fmaf(Lre, Hre, fmaf(-Lim, Him, cr));
            Him = fmaf(Lre, Him, fmaf(Lim, Hre, ci));
            Hre = t;
        }
        const float* pb = proj + (size_t)(b * S_SZ + c * CL) * NPROJ;
        float hre = Hre, him = Him;
        for (int g = 0; g < CL / 8; ++g) {
            float ur[8], ui[8];
#pragma unroll
            for (int i = 0; i < 8; ++i) {
                ur[i] = pb[(g * 8 + i) * NPROJ + h];
                ui[i] = pb[(g * 8 + i) * NPROJ + 64 + h];
            }
            float wr[8], wi[8];
#pragma unroll
            for (int i = 0; i < 8; ++i) {
                float t = fmaf(lre, hre, fmaf(-lim, him, ur[i]));
                him = fmaf(lre, him, fmaf(lim, hre, ui[i]));
                hre = t;
                wr[i] = hre; wi[i] = him;
            }
            *(float4*)&hreL[h * 68 + g * 8]     = make_float4(wr[0], wr[1], wr[2], wr[3]);
            *(float4*)&hreL[h * 68 + g * 8 + 4] = make_float4(wr[4], wr[5], wr[6], wr[7]);
            *(float4*)&himL[h * 68 + g * 8]     = make_float4(wi[0], wi[1], wi[2], wi[3]);
            *(float4*)&himL[h * 68 + g * 8 + 4] = make_float4(wi[4], wi[5], wi[6], wi[7]);
        }
    }

    const int st = tid & 15, ot = tid >> 4;
    const float* db = proj + (size_t)(b * S_SZ + c * CL) * NPROJ;
    float4 dreg[4];
#pragma unroll
    for (int i = 0; i < 4; ++i)
        dreg[i] = *(const float4*)(db + (st * 4 + i) * NPROJ + 128 + ot * 4);

    __syncthreads();

    float acc[4][4];
#pragma unroll
    for (int i = 0; i < 4; ++i) {
        acc[i][0] = dreg[i].x; acc[i][1] = dreg[i].y;
        acc[i][2] = dreg[i].z; acc[i][3] = dreg[i].w;
    }
#pragma unroll 4
    for (int h = 0; h < 64; ++h) {
        float4 hr4 = *(float4*)&hreL[h * 68 + st * 4];
        float4 hi4 = *(float4*)&himL[h * 68 + st * 4];
        float4 cr4 = *(float4*)&ctre[h * 68 + ot * 4];
        float4 ci4 = *(float4*)&ctim[h * 68 + ot * 4];
        float hr[4] = {hr4.x, hr4.y, hr4.z, hr4.w};
        float hi[4] = {hi4.x, hi4.y, hi4.z, hi4.w};
        float cr[4] = {cr4.x, cr4.y, cr4.z, cr4.w};
        float ci[4] = {ci4.x, ci4.y, ci4.z, ci4.w};
#pragma unroll
        for (int i = 0; i < 4; ++i)
#pragma unroll
            for (int j = 0; j < 4; ++j)
                acc[i][j] = fmaf(hr[i], cr[j], fmaf(-hi[i], ci[j], acc[i][j]));
    }
#pragma unroll
    for (int j = 0; j < 4; ++j) {
        float m = fmaxf(fmaxf(acc[0][j], acc[1][j]), fmaxf(acc[2][j], acc[3][j]));
        red[st * 64 + ot * 4 + j] = m;
    }
    __syncthreads();
    if (tid < 64) {
        float mx = red[tid];
#pragma unroll
        for (int q = 1; q < 16; ++q) mx = fmaxf(mx, red[q * 64 + tid]);
        pmax[(size_t)bc * 64 + tid] = mx;
    }
}

// ---------------------------------------------------------------------------
// K4: latent[b][o] = max over chunks of pmax
// ---------------------------------------------------------------------------
__global__ __launch_bounds__(64) void latent_kernel(
        const float* __restrict__ pmax, float* __restrict__ latent) {
    const int b = blockIdx.x;
    const int o = threadIdx.x;
    float mx = -1e30f;
#pragma unroll 8
    for (int c = 0; c < NC; ++c)
        mx = fmaxf(mx, pmax[(size_t)(b * NC + c) * 64 + o]);
    latent[b * 64 + o] = mx;
}

// ---------------------------------------------------------------------------
// K5: fused MLP head.
// ---------------------------------------------------------------------------
__global__ __launch_bounds__(256) void mlp_kernel(
        const float* __restrict__ latent, const float* __restrict__ act,
        const float* __restrict__ W1, const float* __restrict__ b1,
        const float* __restrict__ W2, const float* __restrict__ b2,
        const float* __restrict__ W3, const float* __restrict__ b3,
        float* __restrict__ out) {
    __shared__ float As[64 * 68];      // [k][m]
    __shared__ float Ws[64 * 68];      // [k][n]
    __shared__ float l1L[64 * 65];     // [m][n]
    __shared__ float w2L[64 * 36];     // [k][n2]
    __shared__ float red2[64 * 4];
    const int tid = threadIdx.x;
    const int m0 = blockIdx.x * 64;
    const int b = m0 >> 7;
    const int m = tid & 63;
    const int ng = tid >> 6;

    float acc[16];
#pragma unroll
    for (int j = 0; j < 16; ++j) acc[j] = 0.f;

    for (int kt = 0; kt < 7; ++kt) {
        const int k0 = kt * 64;
#pragma unroll
        for (int rr = 0; rr < 16; ++rr) {
            int e = tid + rr * 256;
            int ml = e >> 6, kk = e & 63;
            int f = k0 + kk;
            float v;
            if (f < 64) {
                v = latent[b * 64 + f];
            } else {
                int a = (m0 + ml) & 127;
                v = act[((size_t)(b * A_SZ + a)) * DIN + (f - 64)];
            }
            As[kk * 68 + ml] = v;
        }
#pragma unroll
        for (int rr = 0; rr < 16; ++rr) {
            int e = tid + rr * 256;
            int n = e >> 6, kk = e & 63;
            Ws[kk * 68 + n] = W1[n * 448 + k0 + kk];
        }
        __syncthreads();
#pragma unroll 4
        for (int kk = 0; kk < 64; ++kk) {
            float a = As[kk * 68 + m];
#pragma unroll
            for (int jq = 0; jq < 4; ++jq) {
                float4 w = *(float4*)&Ws[kk * 68 + ng * 16 + jq * 4];
                acc[jq * 4 + 0] = fmaf(a, w.x, acc[jq * 4 + 0]);
                acc[jq * 4 + 1] = fmaf(a, w.y, acc[jq * 4 + 1]);
                acc[jq * 4 + 2] = fmaf(a, w.z, acc[jq * 4 + 2]);
                acc[jq * 4 + 3] = fmaf(a, w.w, acc[jq * 4 + 3]);
            }
        }
        __syncthreads();
    }
#pragma unroll
    for (int j = 0; j < 16; ++j) {
        int n = ng * 16 + j;
        l1L[m * 65 + n] = tanhf(acc[j] + b1[n]);
    }
#pragma unroll
    for (int rr = 0; rr < 8; ++rr) {
        int e = tid + rr * 256;
        int n2 = e >> 6, kk = e & 63;
        w2L[kk * 36 + n2] = W2[n2 * 64 + kk];
    }
    __syncthreads();
    float acc2[8];
#pragma unroll
    for (int j = 0; j < 8; ++j) acc2[j] = 0.f;
#pragma unroll 4
    for (int kk = 0; kk < 64; ++kk) {
        float v = l1L[m * 65 + kk];
        float4 wa = *(float4*)&w2L[kk * 36 + ng * 8];
        float4 wb = *(float4*)&w2L[kk * 36 + ng * 8 + 4];
        float w[8] = {wa.x, wa.y, wa.z, wa.w, wb.x, wb.y, wb.z, wb.w};
#pragma unroll
        for (int j = 0; j < 8; ++j) acc2[j] = fmaf(v, w[j], acc2[j]);
    }
    float part = 0.f;
#pragma unroll
    for (int j = 0; j < 8; ++j) {
        int n2 = ng * 8 + j;
        part += tanhf(acc2[j] + b2[n2]) * W3[n2];
    }
    red2[m * 4 + ng] = part;
    __syncthreads();
    if (tid < 64) {
        float s = red2[tid * 4 + 0] + red2[tid * 4 + 1] +
                  red2[tid * 4 + 2] + red2[tid * 4 + 3];
        out[m0 + tid] = tanhf(s + b3[0]);
    }
}

// ---------------------------------------------------------------------------
extern "C" void kernel_launch(void* const* d_in, const int* in_sizes, int n_in,
                              void* d_out, int out_size, void* d_ws, size_t ws_size,
                              hipStream_t stream) {
    (void)in_sizes; (void)n_in; (void)out_size; (void)ws_size;
    const float* obs       = (const float*)d_in[0];
    const float* act       = (const float*)d_in[1];
    const float* nu_log    = (const float*)d_in[2];
    const float* theta_log = (const float*)d_in[3];
    const float* gamma_log = (const float*)d_in[4];
    const float* Bre       = (const float*)d_in[5];
    const float* Bim       = (const float*)d_in[6];
    const float* Cre       = (const float*)d_in[7];
    const float* Cim       = (const float*)d_in[8];
    const float* Dw        = (const float*)d_in[9];
    const float* W1        = (const float*)d_in[10];
    const float* b1        = (const float*)d_in[11];
    const float* W2        = (const float*)d_in[12];
    const float* b2        = (const float*)d_in[13];
    const float* W3        = (const float*)d_in[14];
    const float* b3        = (const float*)d_in[15];
    float* outp = (float*)d_out;

    // workspace layout (floats):
    // proj 25165824 | carr 262144 | pmax 131072 | latent 4096 | Whi/Wlo (ushort)
    float* proj   = (float*)d_ws;
    float* carr   = proj + (size_t)25165824;
    float* pmaxb  = carr + 262144;
    float* latent = pmaxb + 131072;
    ushort* Whi   = (ushort*)(latent + 4096);
    ushort* Wlo   = Whi + 92160;

    pack_w_kernel<<<dim3(360), dim3(256), 0, stream>>>(
        Bre, Bim, Dw, gamma_log, Whi, Wlo);
    proj_mfma_kernel<<<dim3((B_SZ * S_SZ) / 128), dim3(256), 0, stream>>>(
        obs, Whi, Wlo, proj);
    carry_kernel<<<dim3(B_SZ * NC), dim3(64), 0, stream>>>(
        proj, nu_log, theta_log, carr);
    ymax_kernel<<<dim3(B_SZ * NC), dim3(256), 0, stream>>>(
        proj, carr, nu_log, theta_log, Cre, Cim, pmaxb);
    latent_kernel<<<dim3(B_SZ), dim3(64), 0, stream>>>(pmaxb, latent);
    mlp_kernel<<<dim3((B_SZ * A_SZ) / 64), dim3(256), 0, stream>>>(
        latent, act, W1, b1, W2, b2, W3, b3, outp);
}

// Round 3
// 435.502 us; speedup vs baseline: 1.3221x; 1.0624x over previous
//
#include <hip/hip_runtime.h>
#include <hip/hip_bf16.h>
#include <math.h>

// Problem constants
#define B_SZ 64
#define S_SZ 2048
#define A_SZ 128
#define DIN 384
#define NH 64      // LRU state dim H
#define DOUT 64
#define NC 32      // chunks per sequence
#define CL 64      // chunk length (NC*CL == S_SZ)
#define NPROJ 192  // h_re(64) | h_im(64) | d(64)

typedef __attribute__((ext_vector_type(8))) short s16x8;
typedef __attribute__((ext_vector_type(8))) unsigned short u16x8;
typedef __attribute__((ext_vector_type(4))) float f32x4;

__device__ inline ushort f2bf(float x) {
    __hip_bfloat16 h = __float2bfloat16(x);
    return *reinterpret_cast<ushort*>(&h);
}
__device__ inline float bf2f(ushort u) {
    union { unsigned int i; float f; } c; c.i = ((unsigned int)u) << 16; return c.f;
}

// ---------------------------------------------------------------------------
// K0a: pack W = [gamma*B_re ; gamma*B_im ; D] into split-bf16 (hi, lo), layout
// [kt][n][40] (k-tile-major, rows padded to 40, pad = 0).
// ---------------------------------------------------------------------------
__global__ __launch_bounds__(256) void pack_w_kernel(
        const float* __restrict__ Bre, const float* __restrict__ Bim,
        const float* __restrict__ Dw, const float* __restrict__ gamma_log,
        ushort* __restrict__ Whi, ushort* __restrict__ Wlo) {
    int idx = blockIdx.x * 256 + threadIdx.x;
    if (idx >= 12 * 192 * 40) return;
    int kk = idx % 40;
    int n  = (idx / 40) % 192;
    int kt = idx / (40 * 192);
    float v = 0.f;
    if (kk < 32) {
        int k = kt * 32 + kk;
        if (n < 64)       v = Bre[n * DIN + k] * expf(gamma_log[n]);
        else if (n < 128) v = Bim[(n - 64) * DIN + k] * expf(gamma_log[n - 64]);
        else              v = Dw[(n - 128) * DIN + k];
    }
    ushort h = f2bf(v);
    ushort l = f2bf(v - bf2f(h));
    Whi[idx] = h;
    Wlo[idx] = l;
}

// ---------------------------------------------------------------------------
// K0b: lamp[t][col] = lambda^(t+1), t=0..63; col<64 -> re(h=col), else im(h=col-64)
// ---------------------------------------------------------------------------
__global__ __launch_bounds__(256) void lamp_kernel(
        const float* __restrict__ nu_log, const float* __restrict__ theta_log,
        float* __restrict__ lamp) {
    int idx = blockIdx.x * 256 + threadIdx.x;   // 0..8191
    if (idx >= 64 * 128) return;
    int s = idx >> 7;
    int col = idx & 127;
    int h = col & 63;
    float t = (float)(s + 1);
    float nu = expf(nu_log[h]);
    float th = expf(theta_log[h]);
    float r = expf(-t * nu);
    lamp[idx] = (col < 64) ? r * cosf(t * th) : r * sinf(t * th);
}

// ---------------------------------------------------------------------------
// K1: proj + local scan fused. GEMM: M=131072, K=384, N=192 (split-bf16, 3
// products -> fp32-class accuracy). BM=128 (= 2 chunks of one b), BN=192.
// Epilogue: d (cols 128..191) -> global; u (cols 0..127) -> LDS; waves 0/1
// scan their chunk (zero-init), write h_local into projbuf cols 0..127 and
// chunk carry.
// ---------------------------------------------------------------------------
__global__ __launch_bounds__(256) void proj_scan_kernel(
        const float* __restrict__ obs, const ushort* __restrict__ Whi,
        const ushort* __restrict__ Wlo, const float* __restrict__ nu_log,
        const float* __restrict__ theta_log, float* __restrict__ projbuf,
        float* __restrict__ carr) {
    __shared__ __align__(16) char smem[128 * 132 * 4];   // 67584 B union
    ushort* Ahi  = (ushort*)smem;          // 128*40
    ushort* Alo  = Ahi + 5120;             // 128*40
    ushort* WhiL = Alo + 5120;             // 192*40
    ushort* WloL = WhiL + 7680;            // 192*40  (total 51200 B)
    float*  u_lds = (float*)smem;          // 128 x 132 floats (67584 B)

    const int tid  = threadIdx.x;
    const int wid  = tid >> 6;
    const int lane = tid & 63;
    const int lrow = lane & 15;
    const int kgrp = lane >> 4;            // 0..3
    const size_t m0 = (size_t)blockIdx.x * 128;

    const int arow  = tid >> 3;            // 0..31 (plus 32*i)
    const int acol4 = (tid & 7) * 4;       // k offset within tile

    f32x4 acc[2][12];
#pragma unroll
    for (int mi = 0; mi < 2; ++mi)
#pragma unroll
        for (int ni = 0; ni < 12; ++ni) acc[mi][ni] = (f32x4){0.f, 0.f, 0.f, 0.f};

#define LOADA(R, KT) do {                                                     \
    const float* base_ = obs + (m0 + arow) * DIN + (KT) * 32 + acol4;         \
    R[0] = *(const float4*)(base_);                                           \
    R[1] = *(const float4*)(base_ + (size_t)32 * DIN);                        \
    R[2] = *(const float4*)(base_ + (size_t)64 * DIN);                        \
    R[3] = *(const float4*)(base_ + (size_t)96 * DIN);                        \
} while (0)

#define WRITEA(R) do {                                                        \
    _Pragma("unroll")                                                         \
    for (int i_ = 0; i_ < 4; ++i_) {                                          \
        int row_ = arow + 32 * i_;                                            \
        ushort4 h_, l_;                                                       \
        h_.x = f2bf(R[i_].x); l_.x = f2bf(R[i_].x - bf2f(h_.x));              \
        h_.y = f2bf(R[i_].y); l_.y = f2bf(R[i_].y - bf2f(h_.y));              \
        h_.z = f2bf(R[i_].z); l_.z = f2bf(R[i_].z - bf2f(h_.z));              \
        h_.w = f2bf(R[i_].w); l_.w = f2bf(R[i_].w - bf2f(h_.w));              \
        *(ushort4*)&Ahi[row_ * 40 + acol4] = h_;                              \
        *(ushort4*)&Alo[row_ * 40 + acol4] = l_;                              \
    }                                                                         \
} while (0)

#define STAGEW(KT) do {                                                       \
    const u16x8* gh_ = (const u16x8*)(Whi + (size_t)(KT) * 7680);             \
    const u16x8* gl_ = (const u16x8*)(Wlo + (size_t)(KT) * 7680);             \
    for (int c_ = tid; c_ < 960; c_ += 256) {                                 \
        *(u16x8*)&WhiL[c_ * 8] = gh_[c_];                                     \
        *(u16x8*)&WloL[c_ * 8] = gl_[c_];                                     \
    }                                                                         \
} while (0)

#define COMPUTE() do {                                                        \
    s16x8 ah0 = *(const s16x8*)&Ahi[(wid * 32 + lrow) * 40 + kgrp * 8];       \
    s16x8 ah1 = *(const s16x8*)&Ahi[(wid * 32 + 16 + lrow) * 40 + kgrp * 8];  \
    s16x8 al0 = *(const s16x8*)&Alo[(wid * 32 + lrow) * 40 + kgrp * 8];       \
    s16x8 al1 = *(const s16x8*)&Alo[(wid * 32 + 16 + lrow) * 40 + kgrp * 8];  \
    _Pragma("unroll")                                                         \
    for (int ni = 0; ni < 12; ++ni) {                                         \
        s16x8 bh = *(const s16x8*)&WhiL[(ni * 16 + lrow) * 40 + kgrp * 8];    \
        s16x8 bl = *(const s16x8*)&WloL[(ni * 16 + lrow) * 40 + kgrp * 8];    \
        acc[0][ni] = __builtin_amdgcn_mfma_f32_16x16x32_bf16(ah0, bh, acc[0][ni], 0, 0, 0); \
        acc[1][ni] = __builtin_amdgcn_mfma_f32_16x16x32_bf16(ah1, bh, acc[1][ni], 0, 0, 0); \
        acc[0][ni] = __builtin_amdgcn_mfma_f32_16x16x32_bf16(al0, bh, acc[0][ni], 0, 0, 0); \
        acc[1][ni] = __builtin_amdgcn_mfma_f32_16x16x32_bf16(al1, bh, acc[1][ni], 0, 0, 0); \
        acc[0][ni] = __builtin_amdgcn_mfma_f32_16x16x32_bf16(ah0, bl, acc[0][ni], 0, 0, 0); \
        acc[1][ni] = __builtin_amdgcn_mfma_f32_16x16x32_bf16(ah1, bl, acc[1][ni], 0, 0, 0); \
    }                                                                         \
} while (0)

    float4 ra[4], rb[4];
    LOADA(ra, 0);
#pragma unroll
    for (int kt2 = 0; kt2 < 6; ++kt2) {
        const int kt = kt2 * 2;
        WRITEA(ra);
        STAGEW(kt);
        LOADA(rb, kt + 1);
        __syncthreads();
        COMPUTE();
        __syncthreads();
        WRITEA(rb);
        STAGEW(kt + 1);
        if (kt + 2 < 12) LOADA(ra, kt + 2);
        __syncthreads();
        COMPUTE();
        __syncthreads();
    }
#undef LOADA
#undef WRITEA
#undef STAGEW
#undef COMPUTE

    // ---- epilogue ----
    // u (cols 0..127) -> LDS [row][132]
#pragma unroll
    for (int ni = 0; ni < 8; ++ni) {
        const int col = ni * 16 + lrow;
#pragma unroll
        for (int mi = 0; mi < 2; ++mi) {
            const int rbase = wid * 32 + mi * 16 + kgrp * 4;
            f32x4 a = acc[mi][ni];
#pragma unroll
            for (int r = 0; r < 4; ++r)
                u_lds[(rbase + r) * 132 + col] = a[r];
        }
    }
    __syncthreads();
    // d (cols 128..191) -> global (independent of LDS)
#pragma unroll
    for (int ni = 8; ni < 12; ++ni) {
        const int col = ni * 16 + lrow;
#pragma unroll
        for (int mi = 0; mi < 2; ++mi) {
            const size_t rbase = m0 + wid * 32 + mi * 16 + kgrp * 4;
            f32x4 a = acc[mi][ni];
#pragma unroll
            for (int r = 0; r < 4; ++r)
                projbuf[(rbase + r) * NPROJ + col] = a[r];
        }
    }
    // waves 0/1: sequential zero-init scan of their chunk; h_local -> cols 0..127
    if (wid < 2) {
        const int h = lane;
        const float nu = expf(nu_log[h]);
        const float rr = expf(-nu);
        const float th = expf(theta_log[h]);
        const float lre = rr * cosf(th), lim = rr * sinf(th);
        const int srow0 = wid * 64;
        float* outb = projbuf + (m0 + srow0) * NPROJ;
        float hre = 0.f, him = 0.f;
        for (int g = 0; g < 8; ++g) {
            float ur[8], ui[8];
#pragma unroll
            for (int i = 0; i < 8; ++i) {
                ur[i] = u_lds[(srow0 + g * 8 + i) * 132 + h];
                ui[i] = u_lds[(srow0 + g * 8 + i) * 132 + 64 + h];
            }
#pragma unroll
            for (int i = 0; i < 8; ++i) {
                float t = fmaf(lre, hre, fmaf(-lim, him, ur[i]));
                him = fmaf(lre, him, fmaf(lim, hre, ui[i]));
                hre = t;
                outb[(g * 8 + i) * NPROJ + h] = hre;
                outb[(g * 8 + i) * NPROJ + 64 + h] = him;
            }
        }
        const int bc = blockIdx.x * 2 + wid;   // global chunk id = b*NC + c
        carr[bc * 128 + h] = hre;
        carr[bc * 128 + 64 + h] = him;
    }
}

// ---------------------------------------------------------------------------
// K2: Hinit[b][c] = combination of carries 0..c-1 (per h). 64 blocks x 64 thr.
// ---------------------------------------------------------------------------
__global__ __launch_bounds__(64) void hinit_kernel(
        const float* __restrict__ carr, const float* __restrict__ nu_log,
        const float* __restrict__ theta_log, float* __restrict__ Hinit) {
    const int b = blockIdx.x;
    const int h = threadIdx.x;
    const float nu = expf(nu_log[h]);
    const float th = expf(theta_log[h]);
    const float rL = expf(-(float)CL * nu);
    const float aL = (float)CL * th;
    const float Lre = rL * cosf(aL), Lim = rL * sinf(aL);
    float Hre = 0.f, Him = 0.f;
    for (int c = 0; c < NC; ++c) {
        const size_t o = (size_t)(b * NC + c) * 128;
        Hinit[o + h] = Hre;
        Hinit[o + 64 + h] = Him;
        float cr = carr[o + h];
        float ci = carr[o + 64 + h];
        float t = fmaf(Lre, Hre, fmaf(-Lim, Him, cr));
        Him = fmaf(Lre, Him, fmaf(Lim, Hre, ci));
        Hre = t;
    }
}

// ---------------------------------------------------------------------------
// K3: per-(b,chunk), fully parallel: h = lamp[t]*Hinit + h_local, then
// y[s][o] = Re(C h) + d, running max over s -> pmax[bc][o].
// ---------------------------------------------------------------------------
__global__ __launch_bounds__(256) void ymax_kernel(
        const float* __restrict__ projbuf, const float* __restrict__ Hinit,
        const float* __restrict__ lamp, const float* __restrict__ Cre,
        const float* __restrict__ Cim, float* __restrict__ pmax) {
    __shared__ float hreL[64 * 68];   // [h][s] stride 68
    __shared__ float himL[64 * 68];
    __shared__ float ctre[64 * 68];   // [h][o] stride 68
    __shared__ float ctim[64 * 68];
    __shared__ float red[16 * 64];
    const int bc = blockIdx.x;
    const int tid = threadIdx.x;

    // d-loads issued early
    const int st = tid & 15, ot = tid >> 4;
    const float* db = projbuf + (size_t)bc * 64 * NPROJ;
    float4 dreg[4];
#pragma unroll
    for (int i = 0; i < 4; ++i)
        dreg[i] = *(const float4*)(db + (st * 4 + i) * NPROJ + 128 + ot * 4);

    // stage C transposed: ct[h][o] = C[o][h]
#pragma unroll
    for (int rr = 0; rr < 16; ++rr) {
        int e = tid + rr * 256;          // 0..4095
        int h = e & 63, o = e >> 6;
        ctre[h * 68 + o] = Cre[o * 64 + h];
        ctim[h * 68 + o] = Cim[o * 64 + h];
    }

    // parallel h-adjust: thread -> (s = tid>>2, 16 h at q*16)
    {
        const int s = tid >> 2;
        const int q = tid & 3;
        const float* hrow = db + (size_t)s * NPROJ;
        const float* lrow = lamp + s * 128;
        const float* Hrow = Hinit + (size_t)bc * 128;
#pragma unroll
        for (int j = 0; j < 4; ++j) {
            const int h0 = q * 16 + j * 4;
            float4 hr = *(const float4*)(hrow + h0);
            float4 hi = *(const float4*)(hrow + 64 + h0);
            float4 pr = *(const float4*)(lrow + h0);
            float4 pi = *(const float4*)(lrow + 64 + h0);
            float4 Hr = *(const float4*)(Hrow + h0);
            float4 Hi = *(const float4*)(Hrow + 64 + h0);
            float re0 = fmaf(pr.x, Hr.x, fmaf(-pi.x, Hi.x, hr.x));
            float re1 = fmaf(pr.y, Hr.y, fmaf(-pi.y, Hi.y, hr.y));
            float re2 = fmaf(pr.z, Hr.z, fmaf(-pi.z, Hi.z, hr.z));
            float re3 = fmaf(pr.w, Hr.w, fmaf(-pi.w, Hi.w, hr.w));
            float im0 = fmaf(pr.x, Hi.x, fmaf(pi.x, Hr.x, hi.x));
            float im1 = fmaf(pr.y, Hi.y, fmaf(pi.y, Hr.y, hi.y));
            float im2 = fmaf(pr.z, Hi.z, fmaf(pi.z, Hr.z, hi.z));
            float im3 = fmaf(pr.w, Hi.w, fmaf(pi.w, Hr.w, hi.w));
            hreL[(h0 + 0) * 68 + s] = re0;
            hreL[(h0 + 1) * 68 + s] = re1;
            hreL[(h0 + 2) * 68 + s] = re2;
            hreL[(h0 + 3) * 68 + s] = re3;
            himL[(h0 + 0) * 68 + s] = im0;
            himL[(h0 + 1) * 68 + s] = im1;
            himL[(h0 + 2) * 68 + s] = im2;
            himL[(h0 + 3) * 68 + s] = im3;
        }
    }
    __syncthreads();

    float acc[4][4];
#pragma unroll
    for (int i = 0; i < 4; ++i) {
        acc[i][0] = dreg[i].x; acc[i][1] = dreg[i].y;
        acc[i][2] = dreg[i].z; acc[i][3] = dreg[i].w;
    }
#pragma unroll 4
    for (int h = 0; h < 64; ++h) {
        float4 hr4 = *(float4*)&hreL[h * 68 + st * 4];
        float4 hi4 = *(float4*)&himL[h * 68 + st * 4];
        float4 cr4 = *(float4*)&ctre[h * 68 + ot * 4];
        float4 ci4 = *(float4*)&ctim[h * 68 + ot * 4];
        float hr[4] = {hr4.x, hr4.y, hr4.z, hr4.w};
        float hi[4] = {hi4.x, hi4.y, hi4.z, hi4.w};
        float cr[4] = {cr4.x, cr4.y, cr4.z, cr4.w};
        float ci[4] = {ci4.x, ci4.y, ci4.z, ci4.w};
#pragma unroll
        for (int i = 0; i < 4; ++i)
#pragma unroll
            for (int j = 0; j < 4; ++j)
                acc[i][j] = fmaf(hr[i], cr[j], fmaf(-hi[i], ci[j], acc[i][j]));
    }
#pragma unroll
    for (int j = 0; j < 4; ++j) {
        float m = fmaxf(fmaxf(acc[0][j], acc[1][j]), fmaxf(acc[2][j], acc[3][j]));
        red[st * 64 + ot * 4 + j] = m;
    }
    __syncthreads();
    if (tid < 64) {
        float mx = red[tid];
#pragma unroll
        for (int q = 1; q < 16; ++q) mx = fmaxf(mx, red[q * 64 + tid]);
        pmax[(size_t)bc * 64 + tid] = mx;
    }
}

// ---------------------------------------------------------------------------
// K4: latent[b][o] = max over chunks of pmax
// ---------------------------------------------------------------------------
__global__ __launch_bounds__(64) void latent_kernel(
        const float* __restrict__ pmax, float* __restrict__ latent) {
    const int b = blockIdx.x;
    const int o = threadIdx.x;
    float mx = -1e30f;
#pragma unroll 8
    for (int c = 0; c < NC; ++c)
        mx = fmaxf(mx, pmax[(size_t)(b * NC + c) * 64 + o]);
    latent[b * 64 + o] = mx;
}

// ---------------------------------------------------------------------------
// K5: fused MLP head.
// ---------------------------------------------------------------------------
__global__ __launch_bounds__(256) void mlp_kernel(
        const float* __restrict__ latent, const float* __restrict__ act,
        const float* __restrict__ W1, const float* __restrict__ b1,
        const float* __restrict__ W2, const float* __restrict__ b2,
        const float* __restrict__ W3, const float* __restrict__ b3,
        float* __restrict__ out) {
    __shared__ float As[64 * 68];      // [k][m]
    __shared__ float Ws[64 * 68];      // [k][n]
    __shared__ float l1L[64 * 65];     // [m][n]
    __shared__ float w2L[64 * 36];     // [k][n2]
    __shared__ float red2[64 * 4];
    const int tid = threadIdx.x;
    const int m0 = blockIdx.x * 64;
    const int b = m0 >> 7;
    const int m = tid & 63;
    const int ng = tid >> 6;

    float acc[16];
#pragma unroll
    for (int j = 0; j < 16; ++j) acc[j] = 0.f;

    for (int kt = 0; kt < 7; ++kt) {
        const int k0 = kt * 64;
#pragma unroll
        for (int rr = 0; rr < 16; ++rr) {
            int e = tid + rr * 256;
            int ml = e >> 6, kk = e & 63;
            int f = k0 + kk;
            float v;
            if (f < 64) {
                v = latent[b * 64 + f];
            } else {
                int a = (m0 + ml) & 127;
                v = act[((size_t)(b * A_SZ + a)) * DIN + (f - 64)];
            }
            As[kk * 68 + ml] = v;
        }
#pragma unroll
        for (int rr = 0; rr < 16; ++rr) {
            int e = tid + rr * 256;
            int n = e >> 6, kk = e & 63;
            Ws[kk * 68 + n] = W1[n * 448 + k0 + kk];
        }
        __syncthreads();
#pragma unroll 4
        for (int kk = 0; kk < 64; ++kk) {
            float a = As[kk * 68 + m];
#pragma unroll
            for (int jq = 0; jq < 4; ++jq) {
                float4 w = *(float4*)&Ws[kk * 68 + ng * 16 + jq * 4];
                acc[jq * 4 + 0] = fmaf(a, w.x, acc[jq * 4 + 0]);
                acc[jq * 4 + 1] = fmaf(a, w.y, acc[jq * 4 + 1]);
                acc[jq * 4 + 2] = fmaf(a, w.z, acc[jq * 4 + 2]);
                acc[jq * 4 + 3] = fmaf(a, w.w, acc[jq * 4 + 3]);
            }
        }
        __syncthreads();
    }
#pragma unroll
    for (int j = 0; j < 16; ++j) {
        int n = ng * 16 + j;
        l1L[m * 65 + n] = tanhf(acc[j] + b1[n]);
    }
#pragma unroll
    for (int rr = 0; rr < 8; ++rr) {
        int e = tid + rr * 256;
        int n2 = e >> 6, kk = e & 63;
        w2L[kk * 36 + n2] = W2[n2 * 64 + kk];
    }
    __syncthreads();
    float acc2[8];
#pragma unroll
    for (int j = 0; j < 8; ++j) acc2[j] = 0.f;
#pragma unroll 4
    for (int kk = 0; kk < 64; ++kk) {
        float v = l1L[m * 65 + kk];
        float4 wa = *(float4*)&w2L[kk * 36 + ng * 8];
        float4 wb = *(float4*)&w2L[kk * 36 + ng * 8 + 4];
        float w[8] = {wa.x, wa.y, wa.z, wa.w, wb.x, wb.y, wb.z, wb.w};
#pragma unroll
        for (int j = 0; j < 8; ++j) acc2[j] = fmaf(v, w[j], acc2[j]);
    }
    float part = 0.f;
#pragma unroll
    for (int j = 0; j < 8; ++j) {
        int n2 = ng * 8 + j;
        part += tanhf(acc2[j] + b2[n2]) * W3[n2];
    }
    red2[m * 4 + ng] = part;
    __syncthreads();
    if (tid < 64) {
        float s = red2[tid * 4 + 0] + red2[tid * 4 + 1] +
                  red2[tid * 4 + 2] + red2[tid * 4 + 3];
        out[m0 + tid] = tanhf(s + b3[0]);
    }
}

// ---------------------------------------------------------------------------
extern "C" void kernel_launch(void* const* d_in, const int* in_sizes, int n_in,
                              void* d_out, int out_size, void* d_ws, size_t ws_size,
                              hipStream_t stream) {
    (void)in_sizes; (void)n_in; (void)out_size; (void)ws_size;
    const float* obs       = (const float*)d_in[0];
    const float* act       = (const float*)d_in[1];
    const float* nu_log    = (const float*)d_in[2];
    const float* theta_log = (const float*)d_in[3];
    const float* gamma_log = (const float*)d_in[4];
    const float* Bre       = (const float*)d_in[5];
    const float* Bim       = (const float*)d_in[6];
    const float* Cre       = (const float*)d_in[7];
    const float* Cim       = (const float*)d_in[8];
    const float* Dw        = (const float*)d_in[9];
    const float* W1        = (const float*)d_in[10];
    const float* b1        = (const float*)d_in[11];
    const float* W2        = (const float*)d_in[12];
    const float* b2        = (const float*)d_in[13];
    const float* W3        = (const float*)d_in[14];
    const float* b3        = (const float*)d_in[15];
    float* outp = (float*)d_out;

    // workspace layout (bytes), with stream-ordered aliasing:
    //   0          : projbuf [131072][192] f32          = 100,663,296
    //   100663296  : region1: carr (K1->K2)  1,048,576  | later pmax+latent (K3->K5)
    //   101711872  : region2: Whi/Wlo (K0->K1)  368,640 | later Hinit (K2->K3) 1,048,576
    //   102760448  : lamp 32,768
    // total 102,793,216 B
    char* base    = (char*)d_ws;
    float* projbuf = (float*)base;
    float* carr    = (float*)(base + 100663296);
    float* pmaxb   = carr;                       // aliases carr (carr dead after K2)
    float* latent  = carr + 131072;              // 524,288 B into region1
    ushort* Whi    = (ushort*)(base + 101711872);
    ushort* Wlo    = Whi + 92160;
    float* Hinit   = (float*)(base + 101711872); // aliases W (dead after K1)
    float* lamp    = (float*)(base + 102760448);

    pack_w_kernel<<<dim3(360), dim3(256), 0, stream>>>(
        Bre, Bim, Dw, gamma_log, Whi, Wlo);
    lamp_kernel<<<dim3(32), dim3(256), 0, stream>>>(nu_log, theta_log, lamp);
    proj_scan_kernel<<<dim3((B_SZ * S_SZ) / 128), dim3(256), 0, stream>>>(
        obs, Whi, Wlo, nu_log, theta_log, projbuf, carr);
    hinit_kernel<<<dim3(B_SZ), dim3(64), 0, stream>>>(
        carr, nu_log, theta_log, Hinit);
    ymax_kernel<<<dim3(B_SZ * NC), dim3(256), 0, stream>>>(
        projbuf, Hinit, lamp, Cre, Cim, pmaxb);
    latent_kernel<<<dim3(B_SZ), dim3(64), 0, stream>>>(pmaxb, latent);
    mlp_kernel<<<dim3((B_SZ * A_SZ) / 64), dim3(256), 0, stream>>>(
        latent, act, W1, b1, W2, b2, W3, b3, outp);
}